// Round 1
// 825.561 us; speedup vs baseline: 1.0864x; 1.0864x over previous
//
#include <hip/hip_runtime.h>
#include <hip/hip_bf16.h>
#include <math.h>

#define BB 256
#define NN 184
#define HH 128
#define FF 8
#define TH 24
#define TF 24
#define KA 160       // augmented K (128 h + x block + pad; k=139 = bias col)
#define NG 512       // 4 gate-parts x 128
#define RPAD 192     // padded row count (12 tiles of 16)
#define STRH 136     // Ah row stride (elems)
#define STRX 40      // Ax row stride (elems)
#define NT 512       // threads per block (8 waves, 2/SIMD -> 256 VGPR budget, no spills)
#define NW3 (NN * 3) // 552 mask words per (b,t)

typedef __attribute__((ext_vector_type(8))) short bf16x8;
typedef __attribute__((ext_vector_type(4))) float f32x4;
typedef __attribute__((ext_vector_type(2))) unsigned u32x2;

__device__ __forceinline__ float sigmoidf_(float x) {
    return 1.0f / (1.0f + __expf(-x));
}
__device__ __forceinline__ float tanhf_(float x) {
    float s = (x >= 0.f) ? 1.f : -1.f;
    float e = __expf(-2.0f * fabsf(x));
    return s * (1.0f - e) / (1.0f + e);
}
__device__ __forceinline__ unsigned short f2bf(float f) {
    unsigned u = __float_as_uint(f);
    u += 0x7fffu + ((u >> 16) & 1u);
    return (unsigned short)(u >> 16);
}
__device__ __forceinline__ unsigned pkbf(float a, float b) {
    __hip_bfloat162 h = __float22bfloat162_rn(make_float2(a, b));
    return *reinterpret_cast<unsigned*>(&h);
}

// ---------------------------------------------------------------------------
// Augmented bf16 weights Wa[512][160] (R, Z, NH, NX). X-block slot layout
// (k-128): 0..7 = fore features f0..f7 (hist: slot0 = p), 8 = xn, 9 = g,
// 11 = bias (pairs with const-1 in Ax[.][11]). NH bias stays in barr[2*128+j].
// ---------------------------------------------------------------------------
__global__ void prep_weights(const float* __restrict__ WhhH, const float* __restrict__ WihH,
                             const float* __restrict__ WhhF, const float* __restrict__ WihF,
                             const float* __restrict__ bihH, const float* __restrict__ bhhH,
                             const float* __restrict__ bihF, const float* __restrict__ bhhF,
                             unsigned short* __restrict__ WaH, unsigned short* __restrict__ WaF,
                             float* __restrict__ barrH, float* __restrict__ barrF) {
    int idx = blockIdx.x * 256 + threadIdx.x;
    if (idx < NG * KA) {
        int jp = idx / KA, k = idx % KA;
        int j = jp & 127, part = jp >> 7;
        float vh = 0.f, vf = 0.f;
        if (part <= 1) {              // R, Z: combined Whh | Wih | bias@slot11
            int row = part * 128 + j;
            if (k < 128) { vh = WhhH[row * 128 + k]; vf = WhhF[row * 128 + k]; }
            else {
                int s = k - 128;
                if (s == 0)  vh = WihH[row * 2 + 1];                 // p (hist)
                if (s == 8)  { vh = WihH[row * 2 + 0]; vf = WihF[row * 10 + 0]; }  // xn
                if (s < 8)   vf = WihF[row * 10 + (s + 1)];          // f0..f7
                if (s == 9)  vf = WihF[row * 10 + 9];                // g
                if (s == 11) { vh = bihH[row] + bhhH[row]; vf = bihF[row] + bhhF[row]; }
            }
        } else if (part == 2) {       // NH: h part of n-gate (no bias fold)
            if (k < 128) { vh = WhhH[(256 + j) * 128 + k]; vf = WhhF[(256 + j) * 128 + k]; }
        } else {                      // NX: x part of n-gate | bih@slot11
            if (k >= 128) {
                int s = k - 128;
                if (s == 0)  vh = WihH[(256 + j) * 2 + 1];
                if (s == 8)  { vh = WihH[(256 + j) * 2 + 0]; vf = WihF[(256 + j) * 10 + 0]; }
                if (s < 8)   vf = WihF[(256 + j) * 10 + (s + 1)];
                if (s == 9)  vf = WihF[(256 + j) * 10 + 9];
                if (s == 11) { vh = bihH[256 + j]; vf = bihF[256 + j]; }
            }
        }
        WaH[idx] = f2bf(vh); WaF[idx] = f2bf(vf);
    }
    if (idx < NG) {
        int j = idx & 127, part = idx >> 7;
        float bh, bf2;
        if (part == 0)      { bh = bihH[j] + bhhH[j];             bf2 = bihF[j] + bhhF[j]; }
        else if (part == 1) { bh = bihH[128 + j] + bhhH[128 + j]; bf2 = bihF[128 + j] + bhhF[128 + j]; }
        else if (part == 2) { bh = bhhH[256 + j];                 bf2 = bhhF[256 + j]; }
        else                { bh = bihH[256 + j];                 bf2 = bihF[256 + j]; }
        barrH[idx] = bh; barrF[idx] = bf2;
    }
}

// ---------------------------------------------------------------------------
// Sparse edge list over adj: rec = (c1, c2, i, j) as float4 (order-invariant
// consumers, atomic append).
// ---------------------------------------------------------------------------
__global__ void prep_edges(const float* __restrict__ angles, const float* __restrict__ adj,
                           float4* __restrict__ edges, int* __restrict__ cnt) {
    int idx = blockIdx.x * 256 + threadIdx.x;
    if (idx < NN * NN && adj[idx] > 0.f) {
        float a = angles[idx];
        int pos = atomicAdd(cnt, 1);
        float4 r;
        r.x = cosf(a);
        r.y = cosf(a - 1.57079632679489662f);
        r.z = __int_as_float(idx / NN);   // i (source)
        r.w = __int_as_float(idx % NN);   // j (dest)
        edges[pos] = r;
    }
}

// ---------------------------------------------------------------------------
// Per-(batch, fore-step) graph precompute: wind-gated bitmask (dest-major),
// dinv, and G[j] = cheb gate pre-activation contribution of the 8 feature
// channels (+ cheb bias). Only the xn channel remains recurrent.
// ---------------------------------------------------------------------------
__global__ __launch_bounds__(256) void prep_graph(
    const float* __restrict__ feature,
    const float4* __restrict__ edges, const int* __restrict__ ecnt,
    const float* __restrict__ cw0, const float* __restrict__ cw1,
    const float* __restrict__ cbb,
    unsigned long long* __restrict__ maskG,   // [B*TF][NN*3]
    float* __restrict__ dinvG,                // [B*TF][NN]
    float* __restrict__ GG)                   // [B*TF][NN]
{
    const int bt = blockIdx.x;
    const int b = bt / TF, t = bt % TF;
    const int tid = threadIdx.x;
    __shared__ float f8[NN * FF];
    __shared__ unsigned long long mT[NN][3];
    __shared__ int dg[NN];
    __shared__ float di[NN];

    const float4* fb4 = (const float4*)(feature + ((long)b * 48 + TH + t) * (NN * FF));
    for (int i = tid; i < (NN * FF) / 4; i += 256) ((float4*)f8)[i] = fb4[i];
    for (int i = tid; i < NN * 3; i += 256) ((unsigned long long*)mT)[i] = 0ull;
    for (int i = tid; i < NN; i += 256) dg[i] = 0;
    __syncthreads();
    const int nE = *ecnt;
    for (int e = tid; e < nE; e += 256) {
        float4 rec = edges[e];
        int ii = __float_as_int(rec.z), jj = __float_as_int(rec.w);
        if (f8[ii * FF] * rec.x + f8[ii * FF + 1] * rec.y >= 0.5f) {
            atomicAdd(&dg[ii], 1);
            atomicOr(&mT[jj][ii >> 6], 1ull << (ii & 63));
        }
    }
    __syncthreads();
    if (tid < NN) di[tid] = (dg[tid] > 0) ? rsqrtf((float)dg[tid]) : 0.f;
    __syncthreads();
    if (tid < NN) {
        int j = tid;
        float acc[8];
        #pragma unroll
        for (int c = 0; c < 8; ++c) acc[c] = 0.f;
        #pragma unroll
        for (int wd = 0; wd < 3; ++wd) {
            unsigned long long m = mT[j][wd];
            while (m) {
                int bp = __ffsll(m) - 1; m &= m - 1;
                int i = wd * 64 + bp;
                float d = di[i];
                #pragma unroll
                for (int c = 0; c < 8; ++c) acc[c] += d * f8[i * FF + c];
            }
        }
        float dj = di[j];
        float hzj = (dj > 0.f) ? 0.f : -1.f;
        float G = cbb[0];
        #pragma unroll
        for (int c = 0; c < 8; ++c) {
            float xv = f8[j * FF + c];
            float y = -dj * acc[c] + hzj * xv;
            G += xv * cw0[c + 1] + y * cw1[c + 1];
        }
        GG[(long)bt * NN + j] = G;
        dinvG[(long)bt * NN + j] = dj;
        #pragma unroll
        for (int wd = 0; wd < 3; ++wd)
            maskG[((long)bt * NN + j) * 3 + wd] = mT[j][wd];
    }
}

// ---------------------------------------------------------------------------
// Persistent fused kernel: one block per batch, 512 threads (8 waves, 2/SIMD
// -> 256-VGPR budget: weights+h+acc all in registers, ZERO spills).
// Per step:  [cheb word-tasks -> B -> gate finalize -> B]  (fore only)
//            [issue t+1 global loads || GEMM+epilogue+fc-partials] -> B
//            [xn reduce || LDS staging writes] -> B
// fc is fused into the GEMM epilogue (shfl-reduce), no fc-MFMA phase.
// ---------------------------------------------------------------------------
__global__ __launch_bounds__(NT, 2) void fused_dgc(
    const float* __restrict__ feature,
    const float* __restrict__ pm25,
    const unsigned short* __restrict__ WaH, const float* __restrict__ barrH,
    const unsigned short* __restrict__ WaF, const float* __restrict__ barrF,
    const float* __restrict__ fchw, const float* __restrict__ fchb,
    const float* __restrict__ fcow, const float* __restrict__ fcob,
    const float* __restrict__ cw0, const float* __restrict__ cw1,
    const unsigned long long* __restrict__ maskG,
    const float* __restrict__ dinvG, const float* __restrict__ GG,
    float* __restrict__ pred)
{
    __shared__ unsigned short Ah[2][RPAD * STRH];   // 104,448 B
    __shared__ unsigned short Ax[RPAD * STRX];      //  15,360 B
    __shared__ float red_s[RPAD * 9];               //   6,912 B (cheb word-partials / fc partials, disjoint lifetimes)
    __shared__ float2 dx_s[NN];                     //   1,472 B (.x = dinv, .y = xn) - one b64 gather in cheb
    __shared__ float G_s[NN];
    __shared__ unsigned long long maskL[NW3];       //   4,416 B

    const int tid = threadIdx.x;
    const int bb = blockIdx.x;
    const int w = tid >> 6, lane = tid & 63, q = lane >> 4, lq = lane & 15;
    const int cg = w;                               // 8 waves = 8 col-groups, all 12 row-tiles each

    for (int i = tid; i < RPAD * STRH; i += NT) Ah[0][i] = 0;
    for (int i = tid; i < RPAD * STRX; i += NT) Ax[i] = 0;
    __syncthreads();
    if (tid < RPAD) Ax[tid * STRX + 11] = (unsigned short)0x3F80;   // const 1.0
    if (tid < NN)
        Ax[tid * STRX + 0] = f2bf(pm25[(long)bb * TH * NN + tid]);  // p at t=0

    // ---- phase weights in registers (A-operand fragments) ----
    bf16x8 wregH[3][4];   // g = R,Z,NH : kc 0..3 (h part)
    bf16x8 wregX[3];      // g = R,Z,NX : kc 4    (x part, incl. bias col)
    float bias2[4], fcb0; // NH bias for the thread's 4 cols
    float4 fw4;           // fc weights for the thread's 4 cols (fp32)

    auto load_phase = [&](const unsigned short* Wa, const float* barr,
                          const float* fcw, const float* fcb) {
        const int jcol = cg * 16 + lq;
        #pragma unroll
        for (int g = 0; g < 3; ++g)
            #pragma unroll
            for (int kc = 0; kc < 4; ++kc)
                wregH[g][kc] = *(const bf16x8*)(Wa + (long)(g * 128 + jcol) * KA + kc * 32 + q * 8);
        wregX[0] = *(const bf16x8*)(Wa + (long)(0 * 128 + jcol) * KA + 128 + q * 8);
        wregX[1] = *(const bf16x8*)(Wa + (long)(1 * 128 + jcol) * KA + 128 + q * 8);
        wregX[2] = *(const bf16x8*)(Wa + (long)(3 * 128 + jcol) * KA + 128 + q * 8);
        #pragma unroll
        for (int rg = 0; rg < 4; ++rg)
            bias2[rg] = barr[2 * 128 + cg * 16 + q * 4 + rg];
        fw4 = *(const float4*)(fcw + cg * 16 + q * 4);
        fcb0 = fcb[0];
    };
    load_phase(WaH, barrH, fchw, fchb);

    const float w00 = cw0[0], w10 = cw1[0];

    float hreg[48];        // fp32 h: row rl*16+lq, cols 16cg+4q+rg
    #pragma unroll
    for (int i = 0; i < 48; ++i) hreg[i] = 0.f;

    int p = 0;
    __syncthreads();       // Ax init visible

    for (int t = 0; t < TH + TF; ++t) {
        // ============ cheb gate (fore steps; xn channel only) =============
        if (t >= TH) {
            // word-parallel gather: 552 (j,word) tasks over 512 threads
            for (int task = tid; task < NW3; task += NT) {
                int j = task / 3, wd = task - j * 3;
                unsigned long long m = maskL[task];
                float acc = 0.f;
                while (m) {
                    int bp = __ffsll(m) - 1; m &= m - 1;
                    float2 dxv = dx_s[wd * 64 + bp];
                    acc += dxv.x * dxv.y;
                }
                red_s[j * 9 + wd] = acc;
            }
            __syncthreads();
            if (tid < NN) {
                int j = tid;
                float2 dxj = dx_s[j];
                float acc = red_s[j * 9] + red_s[j * 9 + 1] + red_s[j * 9 + 2];
                float hzj = (dxj.x > 0.f) ? 0.f : -1.f;
                float y0 = -dxj.x * acc + hzj * dxj.y;
                float g = sigmoidf_(G_s[j] + dxj.y * w00 + y0 * w10);
                Ax[j * STRX + 9] = f2bf(g);
            }
            __syncthreads();
        }

        // ====== issue t+1 staging loads (land during GEMM, write phase 3) ==
        const int t2 = t + 1;
        const bool doF = (t2 >= TH && t2 < TH + TF);
        float4 fstg = {0.f, 0.f, 0.f, 0.f};
        unsigned long long mstg0 = 0ull, mstg1 = 0ull;
        float dstg = 0.f, gstg = 0.f, pstg = 0.f;
        if (doF) {
            const long base = (long)bb * TF + (t2 - TH);
            if (tid < NN * 2)
                fstg = ((const float4*)(feature + ((long)bb * (TH + TF) + t2) * (NN * FF)))[tid];
            mstg0 = maskG[base * NW3 + tid];                       // tid < 512 < 552
            if (tid < NW3 - NT) mstg1 = maskG[base * NW3 + NT + tid];
            if (tid < NN) { dstg = dinvG[base * NN + tid]; gstg = GG[base * NN + tid]; }
        } else if (t2 < TH) {
            if (tid < NN) pstg = pm25[((long)bb * TH + t2) * NN + tid];
        }

        // ========== GRU GEMM (A=weights, B=h) + epilogue + fc partials =====
        #pragma unroll
        for (int rl = 0; rl < 12; ++rl) {
            f32x4 a0 = {0.f,0.f,0.f,0.f}, a1 = {0.f,0.f,0.f,0.f}, a2 = {0.f,0.f,0.f,0.f};
            #pragma unroll
            for (int kc = 0; kc < 4; ++kc) {
                bf16x8 bh = *(const bf16x8*)(&Ah[p][(rl * 16 + lq) * STRH + kc * 32 + q * 8]);
                a0 = __builtin_amdgcn_mfma_f32_16x16x32_bf16(wregH[0][kc], bh, a0, 0, 0, 0);
                a1 = __builtin_amdgcn_mfma_f32_16x16x32_bf16(wregH[1][kc], bh, a1, 0, 0, 0);
                a2 = __builtin_amdgcn_mfma_f32_16x16x32_bf16(wregH[2][kc], bh, a2, 0, 0, 0);
            }
            bf16x8 bx = *(const bf16x8*)(&Ax[(rl * 16 + lq) * STRX + q * 8]);
            a0 = __builtin_amdgcn_mfma_f32_16x16x32_bf16(wregX[0], bx, a0, 0, 0, 0);
            a1 = __builtin_amdgcn_mfma_f32_16x16x32_bf16(wregX[1], bx, a1, 0, 0, 0);
            f32x4 a3 = {0.f,0.f,0.f,0.f};
            a3 = __builtin_amdgcn_mfma_f32_16x16x32_bf16(wregX[2], bx, a3, 0, 0, 0);

            float hn[4];
            #pragma unroll
            for (int rg = 0; rg < 4; ++rg) {
                float rr  = sigmoidf_(a0[rg]);                       // bias folded
                float zz  = sigmoidf_(a1[rg]);
                float nn2 = tanhf_(a3[rg] + rr * (a2[rg] + bias2[rg]));
                float hv  = (1.f - zz) * nn2 + zz * hreg[rl * 4 + rg];
                hreg[rl * 4 + rg] = hv;
                hn[rg] = hv;
            }
            // fc partial (fp32): this lane's 4 cols, reduce over q (cols of cg)
            float pf = hn[0] * fw4.x + hn[1] * fw4.y + hn[2] * fw4.z + hn[3] * fw4.w;
            pf += __shfl_xor(pf, 16);
            pf += __shfl_xor(pf, 32);
            u32x2 pk;
            pk[0] = pkbf(hn[0], hn[1]);
            pk[1] = pkbf(hn[2], hn[3]);
            *(u32x2*)&Ah[p ^ 1][(rl * 16 + lq) * STRH + cg * 16 + q * 4] = pk;
            if (q == 0) red_s[(rl * 16 + lq) * 9 + cg] = pf;         // stride 9: conflict-free
        }
        __syncthreads();

        // ========== phase 3: xn reduce || staging LDS writes ==============
        if (tid < NN) {
            float xn = fcb0;
            #pragma unroll
            for (int c = 0; c < 8; ++c) xn += red_s[tid * 9 + c];
            dx_s[tid].y = xn;
            if (t >= TH) pred[((long)bb * TF + (t - TH)) * NN + tid] = xn;
            if (t < TH + TF - 1) Ax[tid * STRX + 8] = f2bf(xn);
            if (t2 < TH) Ax[tid * STRX + 0] = f2bf(pstg);
        }
        if (doF) {
            if (tid < NN * 2) {
                int row = tid >> 1, hf = tid & 1;
                u32x2 pk2;
                pk2[0] = pkbf(fstg.x, fstg.y);
                pk2[1] = pkbf(fstg.z, fstg.w);
                *(u32x2*)&Ax[row * STRX + hf * 4] = pk2;             // slots 0..7, 8B aligned
            }
            maskL[tid] = mstg0;
            if (tid < NW3 - NT) maskL[NT + tid] = mstg1;
            if (tid < NN) { dx_s[tid].x = dstg; G_s[tid] = gstg; }
        }
        __syncthreads();

        if (t == TH - 1)
            load_phase(WaF, barrF, fcow, fcob);
        p ^= 1;
    }
}

extern "C" void kernel_launch(void* const* d_in, const int* in_sizes, int n_in,
                              void* d_out, int out_size, void* d_ws, size_t ws_size,
                              hipStream_t stream) {
    const float* feature = (const float*)d_in[0];
    const float* pm25    = (const float*)d_in[1];
    const float* adj     = (const float*)d_in[2];
    const float* angles  = (const float*)d_in[3];
    const float* W_ih_h  = (const float*)d_in[4];
    const float* W_hh_h  = (const float*)d_in[5];
    const float* b_ih_h  = (const float*)d_in[6];
    const float* b_hh_h  = (const float*)d_in[7];
    const float* fch_w   = (const float*)d_in[8];
    const float* fch_b   = (const float*)d_in[9];
    const float* cw0     = (const float*)d_in[10];
    const float* cw1     = (const float*)d_in[11];
    const float* cbb     = (const float*)d_in[12];
    const float* W_ih    = (const float*)d_in[13];
    const float* W_hh    = (const float*)d_in[14];
    const float* b_ih    = (const float*)d_in[15];
    const float* b_hh    = (const float*)d_in[16];
    const float* fco_w   = (const float*)d_in[17];
    const float* fco_b   = (const float*)d_in[18];
    float* pred = (float*)d_out;

    char* ws = (char*)d_ws;
    size_t off = 0;
    unsigned short* WaH   = (unsigned short*)(ws + off); off += (size_t)NG * KA * 2;       //   163,840
    unsigned short* WaF   = (unsigned short*)(ws + off); off += (size_t)NG * KA * 2;
    float*          barrH = (float*)(ws + off);          off += (size_t)NG * 4;
    float*          barrF = (float*)(ws + off);          off += (size_t)NG * 4;
    float4*         edges = (float4*)(ws + off);         off += (size_t)NN * NN * 16;      //   541,696
    int*            cnt   = (int*)(ws + off);            off += 16;
    unsigned long long* maskG = (unsigned long long*)(ws + off);
    off += (size_t)BB * TF * NN * 3 * 8;                                                   // 27,131,904
    float* dinvG = (float*)(ws + off); off += (size_t)BB * TF * NN * 4;                    //  4,521,984
    float* GG    = (float*)(ws + off); off += (size_t)BB * TF * NN * 4;                    //  4,521,984

    hipMemsetAsync(cnt, 0, 16, stream);
    prep_weights<<<(NG * KA + 255) / 256, 256, 0, stream>>>(
        W_hh_h, W_ih_h, W_hh, W_ih, b_ih_h, b_hh_h, b_ih, b_hh,
        WaH, WaF, barrH, barrF);
    prep_edges<<<(NN * NN + 255) / 256, 256, 0, stream>>>(angles, adj, edges, cnt);
    prep_graph<<<BB * TF, 256, 0, stream>>>(
        feature, edges, cnt, cw0, cw1, cbb, maskG, dinvG, GG);

    fused_dgc<<<BB, NT, 0, stream>>>(
        feature, pm25, WaH, barrH, WaF, barrF,
        fch_w, fch_b, fco_w, fco_b, cw0, cw1,
        maskG, dinvG, GG, pred);
}

// Round 2
// 707.150 us; speedup vs baseline: 1.2683x; 1.1674x over previous
//
#include <hip/hip_runtime.h>
#include <hip/hip_bf16.h>
#include <math.h>

#define BB 256
#define NN 184
#define HH 128
#define FF 8
#define TH 24
#define TF 24
#define KA 160       // augmented K (128 h + x block + pad; k=139 = bias col)
#define NG 512       // 4 gate-parts x 128
#define RPAD 192     // padded row count (12 tiles of 16)
#define STRH 136     // Ah row stride (elems)
#define NT 1024      // 16 waves, 4/SIMD
#define NW3 552      // mask words per (b,t)
#define LOG2E 1.44269504088896f

// per-(b,t) staging record, 16B-granular, layout mirrored in LDS:
//   fore: [mask 552*8 = 4416][dinv 184*4 = 736][G 184*4 = 736][AxF 184*16 = 2944] = 8832
//   hist: [AxF 2944]  (loaded at LDS offset OFF_AXF)
#define REC_F 8832
#define REC_H 2944
#define OFF_DINV 4416
#define OFF_G 5152
#define OFF_AXF 5888

typedef __attribute__((ext_vector_type(8))) short bf16x8;
typedef __attribute__((ext_vector_type(4))) float f32x4;
typedef __attribute__((ext_vector_type(2))) unsigned u32x2;

__host__ __device__ __forceinline__ long recOff(int b, int t) {
    const long PB = (long)TH * REC_H + (long)TF * REC_F;
    return (long)b * PB + ((t < TH) ? (long)t * REC_H
                                    : (long)TH * REC_H + (long)(t - TH) * REC_F);
}

__device__ __forceinline__ unsigned short f2bf(float f) {
    unsigned u = __float_as_uint(f);
    u += 0x7fffu + ((u >> 16) & 1u);
    return (unsigned short)(u >> 16);
}
__device__ __forceinline__ unsigned pkbf(float a, float b) {
    __hip_bfloat162 h = __float22bfloat162_rn(make_float2(a, b));
    return *reinterpret_cast<unsigned*>(&h);
}
__device__ __forceinline__ void gload16(const void* src, void* dst) {
    __builtin_amdgcn_global_load_lds(
        (const __attribute__((address_space(1))) unsigned int*)src,
        (__attribute__((address_space(3))) unsigned int*)dst, 16, 0, 0);
}

// ---------------------------------------------------------------------------
// Augmented bf16 weights Wa[512][160] (R, Z, NH, NX), PRESCALED:
//   R,Z rows (incl. bias col 139) * log2e      -> sigmoid = rcp(1+exp2(-a))
//   NH,NX rows (incl. bias cols)  * 2*log2e    -> tanh via exp2(-|w|)
// X-block slots (k-128): 0..7 = features (hist: slot0 = p), 8 = xn, 9 = g,
// 11 = bias (pairs with const-1 in AxR[3]). NH bias now ALSO at col 139.
// ---------------------------------------------------------------------------
__global__ void prep_weights(const float* __restrict__ WhhH, const float* __restrict__ WihH,
                             const float* __restrict__ WhhF, const float* __restrict__ WihF,
                             const float* __restrict__ bihH, const float* __restrict__ bhhH,
                             const float* __restrict__ bihF, const float* __restrict__ bhhF,
                             unsigned short* __restrict__ WaH, unsigned short* __restrict__ WaF) {
    int idx = blockIdx.x * 256 + threadIdx.x;
    if (idx >= NG * KA) return;
    int jp = idx / KA, k = idx % KA;
    int j = jp & 127, part = jp >> 7;
    float vh = 0.f, vf = 0.f;
    if (part <= 1) {              // R, Z
        int row = part * 128 + j;
        if (k < 128) { vh = WhhH[row * 128 + k]; vf = WhhF[row * 128 + k]; }
        else {
            int s = k - 128;
            if (s == 0)  vh = WihH[row * 2 + 1];
            if (s < 8)   vf = WihF[row * 10 + (s + 1)];
            if (s == 8)  { vh = WihH[row * 2 + 0]; vf = WihF[row * 10 + 0]; }
            if (s == 9)  vf = WihF[row * 10 + 9];
            if (s == 11) { vh = bihH[row] + bhhH[row]; vf = bihF[row] + bhhF[row]; }
        }
    } else if (part == 2) {       // NH: h part of n-gate + bhh at bias col
        if (k < 128) { vh = WhhH[(256 + j) * 128 + k]; vf = WhhF[(256 + j) * 128 + k]; }
        else if (k == 139) { vh = bhhH[256 + j]; vf = bhhF[256 + j]; }
    } else {                      // NX: x part of n-gate | bih@139
        if (k >= 128) {
            int s = k - 128;
            if (s == 0)  vh = WihH[(256 + j) * 2 + 1];
            if (s < 8)   vf = WihF[(256 + j) * 10 + (s + 1)];
            if (s == 8)  { vh = WihH[(256 + j) * 2 + 0]; vf = WihF[(256 + j) * 10 + 0]; }
            if (s == 9)  vf = WihF[(256 + j) * 10 + 9];
            if (s == 11) { vh = bihH[256 + j]; vf = bihF[256 + j]; }
        }
    }
    float sc = (part <= 1) ? LOG2E : 2.0f * LOG2E;
    WaH[idx] = f2bf(vh * sc);
    WaF[idx] = f2bf(vf * sc);
}

// ---------------------------------------------------------------------------
// Sparse edge list over adj: rec = (c1, c2, i, j) as float4.
// ---------------------------------------------------------------------------
__global__ void prep_edges(const float* __restrict__ angles, const float* __restrict__ adj,
                           float4* __restrict__ edges, int* __restrict__ cnt) {
    int idx = blockIdx.x * 256 + threadIdx.x;
    if (idx < NN * NN && adj[idx] > 0.f) {
        float a = angles[idx];
        int pos = atomicAdd(cnt, 1);
        float4 r;
        r.x = cosf(a);
        r.y = cosf(a - 1.57079632679489662f);
        r.z = __int_as_float(idx / NN);   // i (source)
        r.w = __int_as_float(idx % NN);   // j (dest)
        edges[pos] = r;
    }
}

// ---------------------------------------------------------------------------
// Per-(batch, step) record builder. Hist blocks: AxF = {p,0,...} bf16 rows.
// Fore blocks: wind-gated bitmask, dinv, G (feature-channel cheb gate
// contribution + bias), AxF = bf16 features.
// ---------------------------------------------------------------------------
__global__ __launch_bounds__(256) void prep_graph(
    const float* __restrict__ feature, const float* __restrict__ pm25,
    const float4* __restrict__ edges, const int* __restrict__ ecnt,
    const float* __restrict__ cw0, const float* __restrict__ cw1,
    const float* __restrict__ cbb, char* __restrict__ xrec)
{
    const int bt = blockIdx.x;
    const int b = bt / (TH + TF), tt = bt % (TH + TF);
    const int tid = threadIdx.x;
    __shared__ float f8[NN * FF];
    __shared__ unsigned long long mT[NN][3];
    __shared__ int dg[NN];
    __shared__ float di[NN];

    char* rec = xrec + recOff(b, tt);
    if (tt < TH) {
        if (tid < NN) {
            unsigned short pb = f2bf(pm25[((long)b * TH + tt) * NN + tid]);
            unsigned* dst = (unsigned*)rec + tid * 4;
            dst[0] = (unsigned)pb; dst[1] = 0; dst[2] = 0; dst[3] = 0;
        }
        return;
    }

    const float4* fb4 = (const float4*)(feature + ((long)b * (TH + TF) + tt) * (NN * FF));
    for (int i = tid; i < (NN * FF) / 4; i += 256) ((float4*)f8)[i] = fb4[i];
    for (int i = tid; i < NN * 3; i += 256) ((unsigned long long*)mT)[i] = 0ull;
    for (int i = tid; i < NN; i += 256) dg[i] = 0;
    __syncthreads();
    const int nE = *ecnt;
    for (int e = tid; e < nE; e += 256) {
        float4 r = edges[e];
        int ii = __float_as_int(r.z), jj = __float_as_int(r.w);
        if (f8[ii * FF] * r.x + f8[ii * FF + 1] * r.y >= 0.5f) {
            atomicAdd(&dg[ii], 1);
            atomicOr(&mT[jj][ii >> 6], 1ull << (ii & 63));
        }
    }
    __syncthreads();
    if (tid < NN) di[tid] = (dg[tid] > 0) ? rsqrtf((float)dg[tid]) : 0.f;
    __syncthreads();
    // mask words out
    unsigned long long* mr = (unsigned long long*)rec;
    for (int i = tid; i < NW3; i += 256) mr[i] = ((const unsigned long long*)mT)[i];
    if (tid < NN) {
        int j = tid;
        float acc[8];
        #pragma unroll
        for (int c = 0; c < 8; ++c) acc[c] = 0.f;
        #pragma unroll
        for (int wd = 0; wd < 3; ++wd) {
            unsigned long long m = mT[j][wd];
            while (m) {
                int bp = __ffsll(m) - 1; m &= m - 1;
                int i = wd * 64 + bp;
                float d = di[i];
                #pragma unroll
                for (int c = 0; c < 8; ++c) acc[c] += d * f8[i * FF + c];
            }
        }
        float dj = di[j];
        float hzj = (dj > 0.f) ? 0.f : -1.f;
        float G = cbb[0];
        #pragma unroll
        for (int c = 0; c < 8; ++c) {
            float xv = f8[j * FF + c];
            float y = -dj * acc[c] + hzj * xv;
            G += xv * cw0[c + 1] + y * cw1[c + 1];
        }
        ((float*)(rec + OFF_DINV))[j] = dj;
        ((float*)(rec + OFF_G))[j] = G;
        unsigned short* ax = (unsigned short*)(rec + OFF_AXF) + j * 8;
        #pragma unroll
        for (int c = 0; c < 8; ++c) ax[c] = f2bf(f8[j * FF + c]);
    }
}

// ---------------------------------------------------------------------------
// Persistent fused kernel: one block per batch, 1024 threads (16 waves,
// 4/SIMD). Wave (cg = w&7, rh = w>>3) owns col-group cg, row-half rh.
// Per fore step: [gather+finalize | bar] [stage(t+1) + GEMM + epilogue + fc
// partials | bar] [xn reduce | bar].  Hist: last two phases only.
// All staging is global_load_lds from prepacked records (no VGPR staging).
// ---------------------------------------------------------------------------
__global__ __launch_bounds__(NT, 4) void fused_dgc(
    const unsigned short* __restrict__ WaH,
    const unsigned short* __restrict__ WaF,
    const float* __restrict__ fchw, const float* __restrict__ fchb,
    const float* __restrict__ fcow, const float* __restrict__ fcob,
    const float* __restrict__ cw0, const float* __restrict__ cw1,
    const char* __restrict__ xrec,
    float* __restrict__ pred)
{
    __shared__ unsigned short Ah[2][RPAD * STRH];   // 104,448 B
    __shared__ unsigned short AxR[RPAD * 8];        //   3,072 B (xn, g, -, 1.0, 0..)
    __shared__ __align__(16) char stg[2][8960];     //  17,920 B (+128 pad for padrow reads)
    __shared__ float red_s[RPAD * 9];               //   6,912 B (fc partials)
    __shared__ float2 dx_s[NN];                     //   1,472 B (.x = dinv, .y = xn)
    __shared__ float fcls_f[132];                   //     528 B (fc w fp32 + bias@128)
    __shared__ unsigned short zero16[8];            //      16 B

    const int tid = threadIdx.x;
    const int bb = blockIdx.x;
    const int w = tid >> 6, lane = tid & 63, q = lane >> 4, lq = lane & 15;
    const int cg = w & 7, rh = w >> 3;

    // ---- init (bias const folded into same pass) ----
    for (int i = tid; i < RPAD * STRH; i += NT) Ah[0][i] = 0;
    for (int i = tid; i < RPAD * 8; i += NT)
        AxR[i] = ((i & 7) == 3) ? (unsigned short)0x3F80 : (unsigned short)0;
    if (tid < 8) zero16[tid] = 0;
    if (tid < NN) dx_s[tid] = make_float2(0.f, 0.f);

    // ---- phase weights in registers ----
    bf16x8 wregH[3][4];   // g = R,Z,NH : kc 0..3 (h part)
    bf16x8 wregX[4];      // g = R,Z,NH,NX : x block (incl. bias cols)
    auto load_phase = [&](const unsigned short* Wa, const float* fcw, const float* fcb) {
        const int jcol = cg * 16 + lq;
        #pragma unroll
        for (int g = 0; g < 3; ++g)
            #pragma unroll
            for (int kc = 0; kc < 4; ++kc)
                wregH[g][kc] = *(const bf16x8*)(Wa + (long)(g * 128 + jcol) * KA + kc * 32 + q * 8);
        #pragma unroll
        for (int g = 0; g < 4; ++g)
            wregX[g] = *(const bf16x8*)(Wa + (long)(g * 128 + jcol) * KA + 128 + q * 8);
        if (tid < 132) fcls_f[tid] = (tid < 128) ? fcw[tid] : ((tid == 128) ? fcb[0] : 0.f);
    };
    load_phase(WaH, fchw, fchb);

    // ---- stage t=0 record ----
    if (tid < NN)
        gload16(xrec + recOff(bb, 0) + (long)tid * 16,
                (char*)stg[0] + OFF_AXF + (tid & ~63) * 16);

    const float w00 = cw0[0], w10 = cw1[0];

    float hreg[24];        // fp32 h: row rh*96+rl*16+lq, cols 16cg+4q+rg
    #pragma unroll
    for (int i = 0; i < 24; ++i) hreg[i] = 0.f;

    int p = 0;
    __syncthreads();       // init + stage(0) visible

    for (int t = 0; t < TH + TF; ++t) {
        const unsigned long long* maskS = (const unsigned long long*)stg[p];
        const float* GS = (const float*)(stg[p] + OFF_G);
        const unsigned short* AxFS = (const unsigned short*)(stg[p] + OFF_AXF);

        // ============ cheb gate (fore): gather + finalize in ONE phase =====
        if (t >= TH) {
            const int jg = tid >> 2, wd = tid & 3;
            if (jg < NN) {
                unsigned long long m = (wd < 3) ? maskS[jg * 3 + wd] : 0ull;
                float acc = 0.f;
                while (m) {
                    int bp = __ffsll(m) - 1; m &= m - 1;
                    float2 dxv = dx_s[wd * 64 + bp];
                    acc += dxv.x * dxv.y;
                }
                acc += __shfl_xor(acc, 1);
                acc += __shfl_xor(acc, 2);
                if (wd == 0) {
                    float2 dxj = dx_s[jg];
                    float hzj = (dxj.x > 0.f) ? 0.f : -1.f;
                    float y0 = -dxj.x * acc + hzj * dxj.y;
                    float pre = GS[jg] + dxj.y * w00 + y0 * w10;
                    float g = __builtin_amdgcn_rcpf(1.0f + exp2f(-LOG2E * pre));
                    AxR[jg * 8 + 1] = f2bf(g);
                }
            }
            __syncthreads();
        }

        // ====== issue t+1 staging (async global->LDS, lands by next bar) ===
        const int t2 = t + 1;
        if (t2 < TH + TF) {
            const int nch = (t2 < TH) ? NN : NW3;
            if (tid < nch)
                gload16(xrec + recOff(bb, t2) + (long)tid * 16,
                        (char*)stg[p ^ 1] + ((t2 < TH) ? OFF_AXF : 0) + (tid & ~63) * 16);
        }

        // ========== GRU GEMM + epilogue + fc partials (6 row-tiles) ========
        f32x4 fw = *(const f32x4*)&fcls_f[cg * 16 + q * 4];
        #pragma unroll
        for (int rl = 0; rl < 6; ++rl) {
            const int row = rh * 96 + rl * 16 + lq;
            const int ro = row * STRH;
            f32x4 a0 = {0.f,0.f,0.f,0.f}, a1 = {0.f,0.f,0.f,0.f}, a2 = {0.f,0.f,0.f,0.f};
            #pragma unroll
            for (int kc = 0; kc < 4; ++kc) {
                bf16x8 bh = *(const bf16x8*)(&Ah[p][ro + kc * 32 + q * 8]);
                a0 = __builtin_amdgcn_mfma_f32_16x16x32_bf16(wregH[0][kc], bh, a0, 0, 0, 0);
                a1 = __builtin_amdgcn_mfma_f32_16x16x32_bf16(wregH[1][kc], bh, a1, 0, 0, 0);
                a2 = __builtin_amdgcn_mfma_f32_16x16x32_bf16(wregH[2][kc], bh, a2, 0, 0, 0);
            }
            const unsigned short* bxp = (q == 0) ? (AxFS + row * 8)
                                      : (q == 1) ? (AxR + row * 8) : zero16;
            bf16x8 bx = *(const bf16x8*)bxp;
            a0 = __builtin_amdgcn_mfma_f32_16x16x32_bf16(wregX[0], bx, a0, 0, 0, 0);
            a1 = __builtin_amdgcn_mfma_f32_16x16x32_bf16(wregX[1], bx, a1, 0, 0, 0);
            a2 = __builtin_amdgcn_mfma_f32_16x16x32_bf16(wregX[2], bx, a2, 0, 0, 0);
            f32x4 a3 = {0.f,0.f,0.f,0.f};
            a3 = __builtin_amdgcn_mfma_f32_16x16x32_bf16(wregX[3], bx, a3, 0, 0, 0);

            float hn[4];
            #pragma unroll
            for (int rg = 0; rg < 4; ++rg) {
                // a0,a1 prescaled by log2e; a2,a3 by 2*log2e (biases folded)
                float rr = __builtin_amdgcn_rcpf(1.0f + exp2f(-a0[rg]));
                float zz = __builtin_amdgcn_rcpf(1.0f + exp2f(-a1[rg]));
                float wv = fmaf(rr, a2[rg], a3[rg]);
                unsigned sg = __float_as_uint(wv) & 0x80000000u;
                float e = exp2f(-fabsf(wv));
                float tv = (1.0f - e) * __builtin_amdgcn_rcpf(1.0f + e);
                tv = __uint_as_float(__float_as_uint(tv) ^ sg);
                float hv = fmaf(zz, hreg[rl * 4 + rg] - tv, tv);
                hreg[rl * 4 + rg] = hv;
                hn[rg] = hv;
            }
            // fc partial (fp32): this lane's 4 cols, reduce over q
            float pf = hn[0] * fw.x + hn[1] * fw.y + hn[2] * fw.z + hn[3] * fw.w;
            pf += __shfl_xor(pf, 16);
            pf += __shfl_xor(pf, 32);
            u32x2 pk;
            pk[0] = pkbf(hn[0], hn[1]);
            pk[1] = pkbf(hn[2], hn[3]);
            *(u32x2*)&Ah[p ^ 1][ro + cg * 16 + q * 4] = pk;
            if (q == 0) red_s[row * 9 + cg] = pf;            // stride 9: conflict-free
        }
        __syncthreads();

        // ========== phase 3: xn reduce + dx rebuild ========================
        if (tid < NN) {
            float xn = fcls_f[128];
            #pragma unroll
            for (int c = 0; c < 8; ++c) xn += red_s[tid * 9 + c];
            float dv = 0.f;
            if (t2 >= TH && t2 < TH + TF)
                dv = *(const float*)(stg[p ^ 1] + OFF_DINV + tid * 4);
            dx_s[tid] = make_float2(dv, xn);
            AxR[tid * 8 + 0] = f2bf(xn);
            if (t >= TH) pred[((long)bb * TF + (t - TH)) * NN + tid] = xn;
        }
        __syncthreads();

        if (t == TH - 1)
            load_phase(WaF, fcow, fcob);
        p ^= 1;
    }
}

extern "C" void kernel_launch(void* const* d_in, const int* in_sizes, int n_in,
                              void* d_out, int out_size, void* d_ws, size_t ws_size,
                              hipStream_t stream) {
    const float* feature = (const float*)d_in[0];
    const float* pm25    = (const float*)d_in[1];
    const float* adj     = (const float*)d_in[2];
    const float* angles  = (const float*)d_in[3];
    const float* W_ih_h  = (const float*)d_in[4];
    const float* W_hh_h  = (const float*)d_in[5];
    const float* b_ih_h  = (const float*)d_in[6];
    const float* b_hh_h  = (const float*)d_in[7];
    const float* fch_w   = (const float*)d_in[8];
    const float* fch_b   = (const float*)d_in[9];
    const float* cw0     = (const float*)d_in[10];
    const float* cw1     = (const float*)d_in[11];
    const float* cbb     = (const float*)d_in[12];
    const float* W_ih    = (const float*)d_in[13];
    const float* W_hh    = (const float*)d_in[14];
    const float* b_ih    = (const float*)d_in[15];
    const float* b_hh    = (const float*)d_in[16];
    const float* fco_w   = (const float*)d_in[17];
    const float* fco_b   = (const float*)d_in[18];
    float* pred = (float*)d_out;

    char* ws = (char*)d_ws;
    size_t off = 0;
    unsigned short* WaH   = (unsigned short*)(ws + off); off += (size_t)NG * KA * 2;   //   163,840
    unsigned short* WaF   = (unsigned short*)(ws + off); off += (size_t)NG * KA * 2;
    float4*         edges = (float4*)(ws + off);         off += (size_t)NN * NN * 16;  //   541,696
    int*            cnt   = (int*)(ws + off);            off += 16;
    char*           xrec  = (char*)(ws + off);
    off += (size_t)BB * ((size_t)TH * REC_H + (size_t)TF * REC_F);                     // 72,351,744

    hipMemsetAsync(cnt, 0, 16, stream);
    prep_weights<<<(NG * KA + 255) / 256, 256, 0, stream>>>(
        W_hh_h, W_ih_h, W_hh, W_ih, b_ih_h, b_hh_h, b_ih, b_hh, WaH, WaF);
    prep_edges<<<(NN * NN + 255) / 256, 256, 0, stream>>>(angles, adj, edges, cnt);
    prep_graph<<<BB * (TH + TF), 256, 0, stream>>>(
        feature, pm25, edges, cnt, cw0, cw1, cbb, xrec);

    fused_dgc<<<BB, NT, 0, stream>>>(
        WaH, WaF, fch_w, fch_b, fco_w, fco_b, cw0, cw1, xrec, pred);
}